// Round 11
// baseline (100.583 us; speedup 1.0000x reference)
//
#include <hip/hip_runtime.h>
#include <math.h>
#include <float.h>

#define B_SZ 512
#define C_SZ 1000
#define D_SZ 512
#define K_TOP 10
#define K2 1024                       // [x^2 | x] vs [rd | -2*rd*p]

// ws layout (floats): simi [B][C] only (2.05 MB)
#define SIMI_OFF 0

// Split-C fused GEMM. R10 lesson: grid=256 -> 1 block/CU (8 waves) left the
// load->repack->mfma chain latency-exposed; barriers were irrelevant (R9==R10).
// Fix: BN=8, grid (125,4)=500 blocks -> 2 blocks/CU (16 waves/CU), and a
// paired-K loop (chunks ch and ch+8 read IDENTICAL x floats -> load once,
// emit squared+raw fragments) halving VMEM and loop iterations.
#define BM 128
#define BN 8
#define BNP 16      // LDS rows padded to MFMA fragment height
#define LDB 1032    // B row stride (f16): 2064B rows, 16B-aligned, 2-way alias

using f16x8 = __attribute__((ext_vector_type(8))) _Float16;
using f32x4 = __attribute__((ext_vector_type(4))) float;

#if __has_builtin(__builtin_amdgcn_exp2f)
#define FAST_EXP2(x) __builtin_amdgcn_exp2f(x)
#else
#define FAST_EXP2(x) exp2f(x)
#endif
#if __has_builtin(__builtin_amdgcn_sqrtf)
#define FAST_SQRT(x) __builtin_amdgcn_sqrtf(x)
#else
#define FAST_SQRT(x) sqrtf(x)
#endif
#define LOG2E 1.44269504088896340736f

__device__ __forceinline__ void split2(float v, _Float16& h, _Float16& l) {
    h = (_Float16)v;
    l = (_Float16)(v - (float)h);
}

// ---------------------------------------------------------------------------
// Fused prep+GEMM, split-C, barrier-free K-loop, 2 blocks/CU.
// Phase A: 8 classes/block, ONE row per wave (fully parallel): full-row
//   softmax with HW transcendentals -> [rd | -2*rd*p] hi/lo f16 in LDS rows
//   0..7 (rows 8..15 zeroed); t3 in LDS, folded into simi at epilogue.
// Phase B: 8 paired-K iterations; A-frags straight from global (L2-resident,
//   each x float loaded once), 1-iter register prefetch; B-frags from
//   read-only LDS. 16 MFMA/iter. No barriers after the single Phase-A one.
// ---------------------------------------------------------------------------
__global__ __launch_bounds__(512, 4) void fused_kernel(const float* __restrict__ x,
                                                       const float* __restrict__ protos,
                                                       const float* __restrict__ ex2,
                                                       const float* __restrict__ ex1,
                                                       const int* __restrict__ cls_num,
                                                       float* __restrict__ simi) {
    __shared__ __align__(16) _Float16 BSh[BNP][LDB];
    __shared__ __align__(16) _Float16 BSl[BNP][LDB];
    __shared__ float t3s[BN];

    const int tid  = threadIdx.x;
    const int lane = tid & 63;
    const int w    = tid >> 6;            // 0..7
    const int cx = blockIdx.x;            // 0..124
    const int by = blockIdx.y;            // 0..3
    const int c0 = cx * BN;               // 0..992 (125*8 = 1000 exact)
    const int b0 = by * BM;

    const int mw = w * 16;                // wave tile origin in b
    const int lr = lane & 15;             // A row / C col within fragment
    const int kg = lane >> 4;             // k-group

    // per-lane A row pointer (fragment layout: row=lr, k=kg*8+j)
    const float* xrow = x + (size_t)(b0 + mw + lr) * D_SZ;

    auto load_a = [&](int ch, float4* d) {     // 16 floats of x[:, ch*64 ...]
        const float* xp = xrow + ch * 64 + kg * 8;
        d[0] = *(const float4*)(xp);           // k = base .. +7   (sub0)
        d[1] = *(const float4*)(xp + 4);
        d[2] = *(const float4*)(xp + 32);      // k = base+32 .. +39 (sub1)
        d[3] = *(const float4*)(xp + 36);
    };

    float4 cur[4], nxt[4];
    load_a(0, cur);                       // in flight during all of Phase A

    // ---- Phase A: ONE class row per wave -----------------------------------
    {
        const int lc = w;                 // 0..7
        const int c  = c0 + lc;           // <= 999, always valid
        const size_t rb = (size_t)c * D_SZ + lane * 8;
        float e2v[8], e1v[8], pv[8];
        *(float4*)&e2v[0] = *(const float4*)(ex2 + rb);
        *(float4*)&e2v[4] = *(const float4*)(ex2 + rb + 4);
        *(float4*)&e1v[0] = *(const float4*)(ex1 + rb);
        *(float4*)&e1v[4] = *(const float4*)(ex1 + rb + 4);
        *(float4*)&pv[0]  = *(const float4*)(protos + rb);
        *(float4*)&pv[4]  = *(const float4*)(protos + rb + 4);
        const float N = (float)cls_num[c];

        float v[8], mn = FLT_MAX;
        #pragma unroll
        for (int k = 0; k < 8; k++) {
            v[k] = FAST_SQRT(N * e2v[k] * e2v[k] - e1v[k] * e1v[k]);
            mn = fminf(mn, v[k]);
        }
        #pragma unroll
        for (int off = 1; off < 64; off <<= 1) mn = fminf(mn, __shfl_xor(mn, off));

        float ev[8], s = 0.f, te = 0.f;
        #pragma unroll
        for (int k = 0; k < 8; k++) {
            ev[k] = FAST_EXP2((mn - v[k]) * LOG2E);
            s += ev[k];
            te = fmaf(ev[k] * pv[k], pv[k], te);
        }
        #pragma unroll
        for (int off = 1; off < 64; off <<= 1) {
            s  += __shfl_xor(s, off);
            te += __shfl_xor(te, off);
        }
        const float inv = 1.0f / s;
        if (lane == 0) t3s[lc] = te * inv;

        f16x8 h1, l1, h2, l2;
        #pragma unroll
        for (int k = 0; k < 8; k++) {
            const float rdv = ev[k] * inv;
            const float w2  = -2.0f * rdv * pv[k];
            _Float16 hh, ll;
            split2(rdv, hh, ll); h1[k] = hh; l1[k] = ll;
            split2(w2,  hh, ll); h2[k] = hh; l2[k] = ll;
        }
        const int d = lane * 8;           // feature base 0..504
        *(f16x8*)&BSh[lc][d]         = h1;
        *(f16x8*)&BSh[lc][D_SZ + d]  = h2;
        *(f16x8*)&BSl[lc][d]         = l1;
        *(f16x8*)&BSl[lc][D_SZ + d]  = l2;

        // zero the pad row (8+lc): outputs at lr>=8 are discarded, but keep
        // the B operand clean of junk/NaN.
        f16x8 z;
        #pragma unroll
        for (int k = 0; k < 8; k++) z[k] = (_Float16)0.f;
        *(f16x8*)&BSh[8 + lc][d]        = z;
        *(f16x8*)&BSh[8 + lc][D_SZ + d] = z;
        *(f16x8*)&BSl[8 + lc][d]        = z;
        *(f16x8*)&BSl[8 + lc][D_SZ + d] = z;
    }
    __syncthreads();                      // B tile + t3s complete (only barrier)

    // ---- Phase B: 8 paired-K iterations, no barriers, A from global --------
    f32x4 acc;
    #pragma unroll
    for (int r = 0; r < 4; r++) acc[r] = 0.f;

    for (int ch = 0; ch < 8; ch++) {
        if (ch + 1 < 8) load_a(ch + 1, nxt);

        float av[16];
        *(float4*)&av[0]  = cur[0];
        *(float4*)&av[4]  = cur[1];
        *(float4*)&av[8]  = cur[2];
        *(float4*)&av[12] = cur[3];

        // raw fragments (k2 = 512 + k  ->  B cols 512+...)
        f16x8 rh0, rl0, rh1, rl1;
        #pragma unroll
        for (int k = 0; k < 8; k++) {
            _Float16 hh, ll;
            split2(av[k], hh, ll);     rh0[k] = hh; rl0[k] = ll;
            split2(av[k + 8], hh, ll); rh1[k] = hh; rl1[k] = ll;
        }
        // squared fragments (k2 = k  ->  B cols ch*64+...)
        f16x8 sh0, sl0, sh1, sl1;
        #pragma unroll
        for (int k = 0; k < 8; k++) {
            _Float16 hh, ll;
            const float q0 = av[k] * av[k];
            const float q1 = av[k + 8] * av[k + 8];
            split2(q0, hh, ll); sh0[k] = hh; sl0[k] = ll;
            split2(q1, hh, ll); sh1[k] = hh; sl1[k] = ll;
        }

        const int kbS = ch * 64 + kg * 8;         // squared half: B cols = k
        const int kbR = D_SZ + kbS;               // raw half: B cols = 512+k
        {
            const f16x8 fbh = *(const f16x8*)&BSh[lr][kbS];
            const f16x8 fbl = *(const f16x8*)&BSl[lr][kbS];
            acc = __builtin_amdgcn_mfma_f32_16x16x32_f16(sl0, fbl, acc, 0, 0, 0);
            acc = __builtin_amdgcn_mfma_f32_16x16x32_f16(sh0, fbl, acc, 0, 0, 0);
            acc = __builtin_amdgcn_mfma_f32_16x16x32_f16(sl0, fbh, acc, 0, 0, 0);
            acc = __builtin_amdgcn_mfma_f32_16x16x32_f16(sh0, fbh, acc, 0, 0, 0);
        }
        {
            const f16x8 fbh = *(const f16x8*)&BSh[lr][kbS + 32];
            const f16x8 fbl = *(const f16x8*)&BSl[lr][kbS + 32];
            acc = __builtin_amdgcn_mfma_f32_16x16x32_f16(sl1, fbl, acc, 0, 0, 0);
            acc = __builtin_amdgcn_mfma_f32_16x16x32_f16(sh1, fbl, acc, 0, 0, 0);
            acc = __builtin_amdgcn_mfma_f32_16x16x32_f16(sl1, fbh, acc, 0, 0, 0);
            acc = __builtin_amdgcn_mfma_f32_16x16x32_f16(sh1, fbh, acc, 0, 0, 0);
        }
        {
            const f16x8 fbh = *(const f16x8*)&BSh[lr][kbR];
            const f16x8 fbl = *(const f16x8*)&BSl[lr][kbR];
            acc = __builtin_amdgcn_mfma_f32_16x16x32_f16(rl0, fbl, acc, 0, 0, 0);
            acc = __builtin_amdgcn_mfma_f32_16x16x32_f16(rh0, fbl, acc, 0, 0, 0);
            acc = __builtin_amdgcn_mfma_f32_16x16x32_f16(rl0, fbh, acc, 0, 0, 0);
            acc = __builtin_amdgcn_mfma_f32_16x16x32_f16(rh0, fbh, acc, 0, 0, 0);
        }
        {
            const f16x8 fbh = *(const f16x8*)&BSh[lr][kbR + 32];
            const f16x8 fbl = *(const f16x8*)&BSl[lr][kbR + 32];
            acc = __builtin_amdgcn_mfma_f32_16x16x32_f16(rl1, fbl, acc, 0, 0, 0);
            acc = __builtin_amdgcn_mfma_f32_16x16x32_f16(rh1, fbl, acc, 0, 0, 0);
            acc = __builtin_amdgcn_mfma_f32_16x16x32_f16(rl1, fbh, acc, 0, 0, 0);
            acc = __builtin_amdgcn_mfma_f32_16x16x32_f16(rh1, fbh, acc, 0, 0, 0);
        }

        if (ch + 1 < 8) {
            cur[0] = nxt[0]; cur[1] = nxt[1];
            cur[2] = nxt[2]; cur[3] = nxt[3];
        }
    }

    // Epilogue: C/D layout (verified m89/m91): col = lane&15, row = kg*4+reg.
    // Only cols 0..7 are real classes (BN=8); lr>=8 lanes discard.
    if (lr < BN) {
        const int c = c0 + lr;
        const float t3v = t3s[lr];
        #pragma unroll
        for (int r = 0; r < 4; r++) {
            const int b = b0 + mw + kg * 4 + r;
            simi[(size_t)b * C_SZ + c] = acc[r] + t3v;
        }
    }
}

// ---------------------------------------------------------------------------
// Top-K: per row (one wave each), 10x butterfly min with index tie-break
// (lower index wins == lax.top_k stability). Reads simi directly.
// out[0..B): predict (float-encoded int), out[B..): topk_conf [B][K]
// ---------------------------------------------------------------------------
__global__ __launch_bounds__(256) void topk_kernel(const float* __restrict__ ws,
                                                   const int* __restrict__ proto_label,
                                                   float* __restrict__ out) {
    const float* simi = ws + SIMI_OFF;
    const int wid = threadIdx.x >> 6;
    const int lane = threadIdx.x & 63;
    const int b = blockIdx.x * 4 + wid;

    float vals[16];
    #pragma unroll
    for (int j = 0; j < 16; j++) {
        const int c = lane + j * 64;
        vals[j] = (c < C_SZ) ? simi[(size_t)b * C_SZ + c] : FLT_MAX;
    }

    float kv[K_TOP];
    int ki[K_TOP];
    for (int t = 0; t < K_TOP; t++) {
        float bv = FLT_MAX;
        int bi = 0x7fffffff;
        #pragma unroll
        for (int j = 0; j < 16; j++) {
            const int c = lane + j * 64;
            if (vals[j] < bv) { bv = vals[j]; bi = c; }
        }
        #pragma unroll
        for (int off = 1; off < 64; off <<= 1) {
            const float ov = __shfl_xor(bv, off);
            const int oi = __shfl_xor(bi, off);
            if (ov < bv || (ov == bv && oi < bi)) { bv = ov; bi = oi; }
        }
        kv[t] = bv;
        ki[t] = bi;
        if ((bi & 63) == lane) vals[bi >> 6] = FLT_MAX;
    }

    if (lane == 0) {
        float S = 0.f;
        #pragma unroll
        for (int t = 0; t < K_TOP; t++) S += kv[t];
        float conf[K_TOP];
        #pragma unroll
        for (int t = 0; t < K_TOP; t++) {
            conf[t] = S / kv[t];
            out[B_SZ + b * K_TOP + t] = conf[t];
        }
        int best = 0;
        for (int t = 1; t < K_TOP; t++)
            if (conf[t] > conf[best]) best = t;
        out[b] = (float)proto_label[ki[best]];
    }
}

extern "C" void kernel_launch(void* const* d_in, const int* in_sizes, int n_in,
                              void* d_out, int out_size, void* d_ws, size_t ws_size,
                              hipStream_t stream) {
    const float* x           = (const float*)d_in[0];
    const float* protos      = (const float*)d_in[1];
    const float* ex2         = (const float*)d_in[2];
    const float* ex1         = (const float*)d_in[3];
    const int*   cls_num     = (const int*)d_in[4];
    const int*   proto_label = (const int*)d_in[5];

    float* ws  = (float*)d_ws;
    float* out = (float*)d_out;

    fused_kernel<<<dim3(125, 4), 512, 0, stream>>>(x, protos, ex2, ex1, cls_num,
                                                   ws + SIMI_OFF);

    topk_kernel<<<B_SZ / 4, 256, 0, stream>>>(ws, proto_label, out);
}